// Round 2
// baseline (1017.173 us; speedup 1.0000x reference)
//
#include <hip/hip_runtime.h>
#include <cmath>
#include <cstdint>

// ---------------- static configuration ----------------
// B=32, T=4096, C=3, 128 scales, out 224x224, N_PSI=4096, pad=2047.
// sig = c*32 + b  (96 signals), padded signal length 8190 (store 8192).
// Composite kernel per (scale, class): class 0..6 = interior phase (w mod 7),
// class 7 = w==0 (left-clipped), class 8 = w==223 (right-clipped).
// H rows: [160 zero guard][<=3308 data, 4-aligned][>=160 zero guard], stride 3776 floats.
// xp stored interleaved: xp4[m>>2][sig][m&3] so the main loop does ONE
// global_load_dwordx4 per 4-m step per thread.

constexpr int C_TP     = 8190;
constexpr int C_XROWS  = 8192;   // time rows in xp
constexpr int C_SIGP   = 128;    // padded signals (96 real)
constexpr long long C_HSTRIDE = 3776;
constexpr int C_HGUARD = 160;
constexpr int C_NCLS   = 9;
constexpr int C_RW     = 8;      // w's per chunk
constexpr int C_NW     = 224;

// Replicate numpy: scales = logspace(log10(2), log10(204), 128).astype(f32);
// K = ceil(16*s + 1); d = (4094-K)//2; a = s * (16/4095) in double.
__device__ __forceinline__ void scale_params(int i, float& s32, int& K, int& d, double& a) {
  const double l2   = log10(2.0);
  const double l204 = log10(204.0);
  double step = (l204 - l2) / 127.0;
  double e = (i == 127) ? l204 : ((double)i * step + l2);
  double sv = pow(10.0, e);
  s32 = (float)sv;
  double sp = (double)s32;
  K = (int)ceil(sp * 16.0 + 1.0);
  d = (4094 - K) >> 1;
  a = sp * (16.0 / 4095.0);
}

// ---------------- build reflect-padded, interleaved signals ----------------
// xp4[(p>>2)*128 + sig][p&3]; zeros outside real data. Coalesced writes.
__global__ void k_build_xp(const float* __restrict__ x, float* __restrict__ xp4) {
  int idx = blockIdx.x * blockDim.x + threadIdx.x;   // 8192*128 threads
  int j    = idx & 3;
  int sig  = (idx >> 2) & 127;
  int mblk = idx >> 9;
  int p    = mblk * 4 + j;
  float val = 0.f;
  if (sig < 96 && p < C_TP) {
    int c = sig >> 5;
    int b = sig & 31;
    int t = p - 2047;
    if (t < 0) t = -t;                 // x[2047-p]
    else if (t > 4095) t = 8190 - t;   // x[10237-p]
    val = x[(b * 4096 + t) * 3 + c];
  }
  xp4[idx] = val;
}

// ---------------- build composite kernels H ----------------
__global__ __launch_bounds__(256) void k_build_H(const float* __restrict__ int_psi,
                                                 float* __restrict__ Hbuf,
                                                 int* __restrict__ meta) {
  int i   = blockIdx.x;   // scale
  int cls = blockIdx.y;   // class

  float s32; int K, d; double a;
  scale_params(i, s32, K, d, a);

  int wr = (cls < 7) ? ((cls == 0) ? 7 : cls) : ((cls == 7) ? 0 : 223);
  double ks = 4096.0 / 224.0;
  double sf = ((double)wr + 0.5) * ks - 0.5;
  int t_lo = (int)floor(sf - ks) + 1;
  int t_hi = (int)ceil(sf + ks) - 1;
  if (t_lo < 0) t_lo = 0;
  if (t_hi > 4095) t_hi = 4095;
  int nt  = t_hi - t_lo + 1;   // <= 37
  int npv = nt + 1;            // conv-point weights

  __shared__ double Wt_sh[40];
  __shared__ double v_sh[64];
  __shared__ float  kern_sh[3352];

  // zero this block's full row (replaces the hipMemsetAsync dispatch)
  float* rowFull = Hbuf + (long long)(i * C_NCLS + cls) * C_HSTRIDE;
  for (int q = threadIdx.x; q < (int)C_HSTRIDE; q += 256) rowFull[q] = 0.f;

  if (threadIdx.x == 0) {
    double Z = 0.0;
    for (int t = 0; t < nt; ++t) {
      double wv = 1.0 - fabs(sf - (double)(t + t_lo)) / ks;
      if (wv < 0.0) wv = 0.0;
      Wt_sh[t] = wv; Z += wv;
    }
    for (int t = 0; t < nt; ++t) Wt_sh[t] = Wt_sh[t] / Z;
    double sq = sqrt((double)s32);
    // v[p_lo + q] = -sqrt(s) * (Wt[q-1] - Wt[q]),  coef = -sqrt(s)*(conv[t+d+1]-conv[t+d])
    for (int q = 0; q <= nt; ++q) {
      double wm1 = (q >= 1)  ? Wt_sh[q - 1] : 0.0;
      double w0  = (q < nt)  ? Wt_sh[q]     : 0.0;
      v_sh[q] = -sq * (wm1 - w0);
    }
  }

  // flipped gathered wavelet: kernW[tau] = int_psi[clip(floor((K-1-tau)/a))]
  float* kernp = kern_sh + 40;
  int fillN = K + 80;
  for (int q = threadIdx.x; q < fillN; q += 256) {
    int tau = q - 40;
    float kv = 0.f;
    if (tau >= 0 && tau < K) {
      int u = K - 1 - tau;
      int jj = (int)floor((double)u / a);
      jj = jj < 0 ? 0 : (jj > 4095 ? 4095 : jj);
      kv = int_psi[jj];
    }
    kern_sh[q] = kv;
  }
  __syncthreads();

  int p_lo = t_lo + d;
  int Lh   = K + npv - 1;
  int kr   = (cls == 0) ? 1 : ((cls == 8) ? 31 : 0);
  int off0 = p_lo - 128 * kr;
  int shift = off0 & 3;
  int offA  = off0 - shift;
  int rowLen = (shift + Lh + 3) & ~3;

  float* row = Hbuf + (long long)(i * C_NCLS + cls) * C_HSTRIDE + C_HGUARD;
  for (int q = threadIdx.x; q < Lh; q += 256) {
    double acc = 0.0;
    for (int t = 0; t < npv; ++t) acc += v_sh[t] * (double)kernp[q - t];
    row[shift + q] = (float)acc;
  }
  if (threadIdx.x == 0) {
    meta[(i * C_NCLS + cls) * 2 + 0] = offA;
    meta[(i * C_NCLS + cls) * 2 + 1] = rowLen;
  }
}

// ---------------- main: OT[scale][w][sig] = sum_m xp[sig][m] * H_w[m] ----------------
// 1D grid, scale-interleaved for load balance: i = bx & 127, chunk = bx >> 7.
__global__ __launch_bounds__(128) void k_cwt_main(const float4* __restrict__ xp4,
                                                  const float* __restrict__ Hbuf,
                                                  const int* __restrict__ meta,
                                                  float* __restrict__ OT) {
  int bx    = blockIdx.x;       // 0..3583
  int i     = bx & 127;         // scale (interleaved across dispatch order)
  int chunk = bx >> 7;          // 0..27
  int sig   = threadIdx.x;      // 0..127 (>=96 compute zeros)

  float acc[C_RW];
  const float* P[C_RW];
  int U0 = 0x7fffffff, U1 = 0;
#pragma unroll
  for (int j = 0; j < C_RW; ++j) {
    acc[j] = 0.f;
    int w = chunk * C_RW + j;
    int cls = (w == 0) ? 7 : ((w == 223) ? 8 : (w % 7));
    int k = w / 7;
    int base = i * C_NCLS + cls;
    int offA = meta[base * 2 + 0];
    int rl   = meta[base * 2 + 1];
    int start = offA + 128 * k;           // 4-aligned by construction
    if (start < U0) U0 = start;
    if (start + rl > U1) U1 = start + rl;
    P[j] = Hbuf + ((long long)base * C_HSTRIDE + C_HGUARD - start);
  }

  const float4* xr = xp4 + ((long long)(U0 >> 2) * C_SIGP + sig);
  float4 xv = *xr; xr += C_SIGP;
  for (int m = U0; m < U1; m += 4) {
    float4 xn = *xr; xr += C_SIGP;        // prefetch next (guarded by buffer size)
    float4 h[C_RW];
#pragma unroll
    for (int j = 0; j < C_RW; ++j) h[j] = *(const float4*)(P[j] + m);  // uniform -> s_load
#pragma unroll
    for (int j = 0; j < C_RW; ++j)
      acc[j] += xv.x * h[j].x + xv.y * h[j].y + xv.z * h[j].z + xv.w * h[j].w;
    xv = xn;
  }

#pragma unroll
  for (int j = 0; j < C_RW; ++j) {
    int w = chunk * C_RW + j;
    OT[((long long)i * C_NW + w) * C_SIGP + sig] = acc[j];
  }
}

// ---------------- final: scale-dim bilinear upsample 128->224 + layout ----------------
// One thread per (b,h,w); writes 3 consecutive floats (coalesced across w).
__global__ __launch_bounds__(256) void k_final(const float* __restrict__ OT,
                                               float* __restrict__ out) {
  int idx = blockIdx.x * blockDim.x + threadIdx.x;
  if (idx >= 32 * 224 * 224) return;
  int w = idx % 224;
  int r = idx / 224;
  int h = r % 224;
  int b = r / 224;

  float inv = 128.0f / 224.0f;               // f32 like jax
  float sg = ((float)h + 0.5f) * inv - 0.5f;
  float sgf = floorf(sg);
  int s0 = (int)sgf;
  float fr = sg - sgf;

  int obase = ((b * 224 + h) * 224 + w) * 3;
#pragma unroll
  for (int c = 0; c < 3; ++c) {
    int sigi = c * 32 + b;
    float v;
    if (s0 < 0) {
      v = OT[(long long)(0 * 224 + w) * C_SIGP + sigi];
    } else if (s0 >= 127) {
      v = OT[((long long)127 * 224 + w) * C_SIGP + sigi];
    } else {
      float a0 = OT[((long long)s0 * 224 + w) * C_SIGP + sigi];
      float a1 = OT[((long long)(s0 + 1) * 224 + w) * C_SIGP + sigi];
      v = (1.0f - fr) * a0 + fr * a1;
    }
    out[obase + c] = v;
  }
}

// ---------------- launch ----------------
extern "C" void kernel_launch(void* const* d_in, const int* in_sizes, int n_in,
                              void* d_out, int out_size, void* d_ws, size_t ws_size,
                              hipStream_t stream) {
  const float* x       = (const float*)d_in[0];   // (32,4096,3) f32
  const float* int_psi = (const float*)d_in[1];   // (4096,) f32
  float* out = (float*)d_out;

  // workspace layout: xp4 (4 MB) | Hbuf (17.4 MB) | meta (9 KB) | OT (14.7 MB)
  float* xp4  = (float*)d_ws;                                   // 8192*128 floats
  float* Hbuf = xp4 + (long long)C_XROWS * C_SIGP;              // 1152*3776 floats
  int*   meta = (int*)(Hbuf + (long long)128 * C_NCLS * C_HSTRIDE); // 2304 ints
  float* OT   = (float*)(meta + 2304);                          // 128*224*128 floats

  k_build_xp<<<dim3((C_XROWS * C_SIGP) / 256), dim3(256), 0, stream>>>(x, xp4);
  k_build_H<<<dim3(128, C_NCLS), dim3(256), 0, stream>>>(int_psi, Hbuf, meta);
  k_cwt_main<<<dim3(28 * 128), dim3(128), 0, stream>>>((const float4*)xp4, Hbuf, meta, OT);
  k_final<<<dim3((32 * 224 * 224 + 255) / 256), dim3(256), 0, stream>>>(OT, out);
}

// Round 3
// 421.576 us; speedup vs baseline: 2.4128x; 2.4128x over previous
//
#include <hip/hip_runtime.h>
#include <cmath>
#include <cstdint>

// ---------------- static configuration ----------------
// B=32, T=4096, C=3, 128 scales, out 224x224, N_PSI=4096, pad=2047.
// sig = c*32 + b  (96 signals), padded signal length 8190 (store 8192).
// Composite kernel per (scale, class): class 0..6 = interior phase (w mod 7),
// class 7 = w==0 (left-clipped), class 8 = w==223 (right-clipped).
// H rows: [160 zero guard][<=3308 data, 4-aligned][>=140 zero guard], stride 3776 floats.
// xp stored interleaved: xp4[m>>2][sig][m&3] -> one global_load_dwordx4 per 4 m.
// Main kernel: block = (scale, 4 w's, m-piece of 1024); scale-major dispatch
// (heavy scales first) keeps co-resident blocks on the same ~135 KB of H (L2-hot);
// m-pieces bound the critical path; fp32 atomicAdd combines pieces.

constexpr int C_TP     = 8190;
constexpr int C_XROWS  = 8192;   // time rows in xp
constexpr int C_SIGP   = 128;    // padded signals (96 real)
constexpr long long C_HSTRIDE = 3776;
constexpr int C_HGUARD = 160;
constexpr int C_NCLS   = 9;
constexpr int C_RW     = 4;      // w's per block
constexpr int C_NCH    = 56;     // 224 / C_RW
constexpr int C_NW     = 224;
constexpr int C_M      = 1024;   // m per piece
constexpr int C_NP     = 4;      // max pieces: (3308 + 55 + 8)/1024 -> 4

// Replicate numpy: scales = logspace(log10(2), log10(204), 128).astype(f32);
// K = ceil(16*s + 1); d = (4094-K)//2; a = s * (16/4095) in double.
__device__ __forceinline__ void scale_params(int i, float& s32, int& K, int& d, double& a) {
  const double l2   = log10(2.0);
  const double l204 = log10(204.0);
  double step = (l204 - l2) / 127.0;
  double e = (i == 127) ? l204 : ((double)i * step + l2);
  double sv = pow(10.0, e);
  s32 = (float)sv;
  double sp = (double)s32;
  K = (int)ceil(sp * 16.0 + 1.0);
  d = (4094 - K) >> 1;
  a = sp * (16.0 / 4095.0);
}

// ---------------- build reflect-padded, interleaved signals ----------------
// xp4[(p>>2)*128 + sig][p&3]; zeros outside real data. Coalesced writes.
__global__ void k_build_xp(const float* __restrict__ x, float* __restrict__ xp4) {
  int idx = blockIdx.x * blockDim.x + threadIdx.x;   // 8192*128 threads
  int j    = idx & 3;
  int sig  = (idx >> 2) & 127;
  int mblk = idx >> 9;
  int p    = mblk * 4 + j;
  float val = 0.f;
  if (sig < 96 && p < C_TP) {
    int c = sig >> 5;
    int b = sig & 31;
    int t = p - 2047;
    if (t < 0) t = -t;                 // x[2047-p]
    else if (t > 4095) t = 8190 - t;   // x[10237-p]
    val = x[(b * 4096 + t) * 3 + c];
  }
  xp4[idx] = val;
}

// ---------------- zero OT (atomic accumulation target) ----------------
__global__ void k_zero(float* __restrict__ p, int n4) {
  int idx = blockIdx.x * blockDim.x + threadIdx.x;
  if (idx < n4) ((float4*)p)[idx] = make_float4(0.f, 0.f, 0.f, 0.f);
}

// ---------------- build composite kernels H ----------------
__global__ __launch_bounds__(256) void k_build_H(const float* __restrict__ int_psi,
                                                 float* __restrict__ Hbuf,
                                                 int* __restrict__ meta) {
  int i   = blockIdx.x;   // scale
  int cls = blockIdx.y;   // class

  float s32; int K, d; double a;
  scale_params(i, s32, K, d, a);

  int wr = (cls < 7) ? ((cls == 0) ? 7 : cls) : ((cls == 7) ? 0 : 223);
  double ks = 4096.0 / 224.0;
  double sf = ((double)wr + 0.5) * ks - 0.5;
  int t_lo = (int)floor(sf - ks) + 1;
  int t_hi = (int)ceil(sf + ks) - 1;
  if (t_lo < 0) t_lo = 0;
  if (t_hi > 4095) t_hi = 4095;
  int nt  = t_hi - t_lo + 1;   // <= 37
  int npv = nt + 1;            // conv-point weights

  __shared__ double Wt_sh[40];
  __shared__ double v_sh[64];
  __shared__ float  kern_sh[3352];

  // zero this block's full row
  float* rowFull = Hbuf + (long long)(i * C_NCLS + cls) * C_HSTRIDE;
  for (int q = threadIdx.x; q < (int)C_HSTRIDE; q += 256) rowFull[q] = 0.f;

  if (threadIdx.x == 0) {
    double Z = 0.0;
    for (int t = 0; t < nt; ++t) {
      double wv = 1.0 - fabs(sf - (double)(t + t_lo)) / ks;
      if (wv < 0.0) wv = 0.0;
      Wt_sh[t] = wv; Z += wv;
    }
    for (int t = 0; t < nt; ++t) Wt_sh[t] = Wt_sh[t] / Z;
    double sq = sqrt((double)s32);
    // v[p_lo + q] = -sqrt(s) * (Wt[q-1] - Wt[q])
    for (int q = 0; q <= nt; ++q) {
      double wm1 = (q >= 1)  ? Wt_sh[q - 1] : 0.0;
      double w0  = (q < nt)  ? Wt_sh[q]     : 0.0;
      v_sh[q] = -sq * (wm1 - w0);
    }
  }

  // flipped gathered wavelet: kernW[tau] = int_psi[clip(floor((K-1-tau)/a))]
  float* kernp = kern_sh + 40;
  int fillN = K + 80;
  for (int q = threadIdx.x; q < fillN; q += 256) {
    int tau = q - 40;
    float kv = 0.f;
    if (tau >= 0 && tau < K) {
      int u = K - 1 - tau;
      int jj = (int)floor((double)u / a);
      jj = jj < 0 ? 0 : (jj > 4095 ? 4095 : jj);
      kv = int_psi[jj];
    }
    kern_sh[q] = kv;
  }
  __syncthreads();

  int p_lo = t_lo + d;
  int Lh   = K + npv - 1;
  int kr   = (cls == 0) ? 1 : ((cls == 8) ? 31 : 0);
  int off0 = p_lo - 128 * kr;
  int shift = off0 & 3;
  int offA  = off0 - shift;
  int rowLen = (shift + Lh + 3) & ~3;

  float* row = Hbuf + (long long)(i * C_NCLS + cls) * C_HSTRIDE + C_HGUARD;
  for (int q = threadIdx.x; q < Lh; q += 256) {
    double acc = 0.0;
    for (int t = 0; t < npv; ++t) acc += v_sh[t] * (double)kernp[q - t];
    row[shift + q] = (float)acc;
  }
  if (threadIdx.x == 0) {
    meta[(i * C_NCLS + cls) * 2 + 0] = offA;
    meta[(i * C_NCLS + cls) * 2 + 1] = rowLen;
  }
}

// ---------------- main: OT[scale][w][sig] += sum_{m in piece} xp[m][sig]*H_w[m] ----------
// grid (piece, chunk, scale'), scale' reversed so heavy scales dispatch first.
__global__ __launch_bounds__(128) void k_cwt_main(const float4* __restrict__ xp4,
                                                  const float* __restrict__ Hbuf,
                                                  const int* __restrict__ meta,
                                                  float* __restrict__ OT) {
  int piece = blockIdx.x;           // 0..3
  int chunk = blockIdx.y;           // 0..55
  int i     = 127 - blockIdx.z;     // heavy scales first
  int sig   = threadIdx.x;          // 0..127 (>=96 compute zeros)

  float acc[C_RW];
  const float* P[C_RW];
  int U0 = 0x7fffffff, U1 = 0;
#pragma unroll
  for (int j = 0; j < C_RW; ++j) {
    acc[j] = 0.f;
    int w = chunk * C_RW + j;
    int cls = (w == 0) ? 7 : ((w == 223) ? 8 : (w % 7));
    int k = w / 7;
    int base = i * C_NCLS + cls;
    int offA = meta[base * 2 + 0];
    int rl   = meta[base * 2 + 1];
    int start = offA + 128 * k;           // 4-aligned by construction
    if (start < U0) U0 = start;
    if (start + rl > U1) U1 = start + rl;
    P[j] = Hbuf + ((long long)base * C_HSTRIDE + C_HGUARD - start);
  }

  int m0 = U0 + piece * C_M;
  int m1 = m0 + C_M; if (m1 > U1) m1 = U1;
  if (m0 >= m1) return;

  // unroll x2: 8 m per iteration; overshoot reads land in H zero-guard (safe)
  const float4* xr = xp4 + ((long long)(m0 >> 2) * C_SIGP + sig);
  for (int m = m0; m < m1; m += 8) {
    float4 xa = xr[0];
    float4 xb = xr[C_SIGP];
    xr += 2 * C_SIGP;
    float4 ha[C_RW], hb[C_RW];
#pragma unroll
    for (int j = 0; j < C_RW; ++j) {
      ha[j] = *(const float4*)(P[j] + m);      // uniform -> s_load_dwordx4
      hb[j] = *(const float4*)(P[j] + m + 4);
    }
#pragma unroll
    for (int j = 0; j < C_RW; ++j) {
      acc[j] += xa.x * ha[j].x + xa.y * ha[j].y + xa.z * ha[j].z + xa.w * ha[j].w;
      acc[j] += xb.x * hb[j].x + xb.y * hb[j].y + xb.z * hb[j].z + xb.w * hb[j].w;
    }
  }

#pragma unroll
  for (int j = 0; j < C_RW; ++j) {
    int w = chunk * C_RW + j;
    atomicAdd(&OT[((long long)i * C_NW + w) * C_SIGP + sig], acc[j]);
  }
}

// ---------------- final: scale-dim bilinear upsample 128->224 + layout ----------------
// block = (wtile of 8, h). Stage the two needed OT scale-rows in LDS (coalesced),
// then 256 threads = (b, w') each write 3 consecutive output floats.
__global__ __launch_bounds__(256) void k_final(const float* __restrict__ OT,
                                               float* __restrict__ out) {
  int wt = blockIdx.x;    // 0..27
  int h  = blockIdx.y;    // 0..223

  float inv = 128.0f / 224.0f;               // f32 like jax
  float sg = ((float)h + 0.5f) * inv - 0.5f;
  float sgf = floorf(sg);
  int s0 = (int)sgf;
  float fr = sg - sgf;
  int r0, r1;
  if (s0 < 0)        { r0 = 0;   r1 = 0;   fr = 0.f; }
  else if (s0 >= 127){ r0 = 127; r1 = 127; fr = 0.f; }
  else               { r0 = s0;  r1 = s0 + 1; }

  __shared__ float sh0[8 * 132];
  __shared__ float sh1[8 * 132];
  for (int q = threadIdx.x; q < 1024; q += 256) {
    int wp  = q >> 7;
    int sg2 = q & 127;
    int wg  = wt * 8 + wp;
    sh0[wp * 132 + sg2] = OT[((long long)r0 * C_NW + wg) * C_SIGP + sg2];
    sh1[wp * 132 + sg2] = OT[((long long)r1 * C_NW + wg) * C_SIGP + sg2];
  }
  __syncthreads();

  int b  = threadIdx.x >> 3;    // 0..31
  int wp = threadIdx.x & 7;     // 0..7
  int obase = ((b * 224 + h) * 224 + wt * 8 + wp) * 3;
#pragma unroll
  for (int c = 0; c < 3; ++c) {
    int sidx = wp * 132 + c * 32 + b;
    float a0 = sh0[sidx];
    float a1 = sh1[sidx];
    out[obase + c] = (1.0f - fr) * a0 + fr * a1;
  }
}

// ---------------- launch ----------------
extern "C" void kernel_launch(void* const* d_in, const int* in_sizes, int n_in,
                              void* d_out, int out_size, void* d_ws, size_t ws_size,
                              hipStream_t stream) {
  const float* x       = (const float*)d_in[0];   // (32,4096,3) f32
  const float* int_psi = (const float*)d_in[1];   // (4096,) f32
  float* out = (float*)d_out;

  // workspace layout: xp4 (4 MB) | Hbuf (17.4 MB) | meta (9 KB) | OT (14.7 MB)
  float* xp4  = (float*)d_ws;                                   // 8192*128 floats
  float* Hbuf = xp4 + (long long)C_XROWS * C_SIGP;              // 1152*3776 floats
  int*   meta = (int*)(Hbuf + (long long)128 * C_NCLS * C_HSTRIDE); // 2304 ints
  float* OT   = (float*)(meta + 2304);                          // 128*224*128 floats

  int otN = 128 * C_NW * C_SIGP;
  k_zero<<<dim3(otN / 4 / 256), dim3(256), 0, stream>>>(OT, otN / 4);
  k_build_xp<<<dim3((C_XROWS * C_SIGP) / 256), dim3(256), 0, stream>>>(x, xp4);
  k_build_H<<<dim3(128, C_NCLS), dim3(256), 0, stream>>>(int_psi, Hbuf, meta);
  k_cwt_main<<<dim3(C_NP, C_NCH, 128), dim3(128), 0, stream>>>((const float4*)xp4, Hbuf, meta, OT);
  k_final<<<dim3(28, 224), dim3(256), 0, stream>>>(OT, out);
}

// Round 4
// 414.522 us; speedup vs baseline: 2.4538x; 1.0170x over previous
//
#include <hip/hip_runtime.h>
#include <cmath>
#include <cstdint>

// ---------------- static configuration ----------------
// B=32, T=4096, C=3, 128 scales, out 224x224, N_PSI=4096, pad=2047.
// sig = c*32 + b  (96 signals), padded signal length 8190 (store 8192).
// Composite kernel per (scale, class): class 0..6 = interior phase (w mod 7),
// class 7 = w==0 (left-clipped), class 8 = w==223 (right-clipped).
// H rows: [160 zero guard][<=3308 data, 4-aligned][>=308 zero guard], stride 3776 floats.
// xp stored interleaved: xp4[m>>2][sig][m&3] -> one global_load_dwordx4 per 4 m.
// Main kernel: block = (scale, 4 w's, m-piece of 1024); scale-major dispatch
// (heavy scales first) keeps co-resident blocks on the same ~135 KB of H (L2-hot);
// m-pieces bound the critical path; fp32 atomicAdd combines pieces.
// Round 4: software-pipelined rotate — x prefetched 2 iterations ahead (VGPR),
// H quads prefetched 1 iteration ahead (SGPR) — so the compiler's waitcnt for
// iteration n's operands overlaps iteration n-1's FMAs instead of draining.

constexpr int C_TP     = 8190;
constexpr int C_XROWS  = 8192;   // time rows in xp
constexpr int C_SIGP   = 128;    // padded signals (96 real)
constexpr long long C_HSTRIDE = 3776;
constexpr int C_HGUARD = 160;
constexpr int C_NCLS   = 9;
constexpr int C_RW     = 4;      // w's per block
constexpr int C_NCH    = 56;     // 224 / C_RW
constexpr int C_NW     = 224;
constexpr int C_M      = 1024;   // m per piece
constexpr int C_NP     = 4;      // max pieces

// Replicate numpy: scales = logspace(log10(2), log10(204), 128).astype(f32);
// K = ceil(16*s + 1); d = (4094-K)//2; a = s * (16/4095) in double.
__device__ __forceinline__ void scale_params(int i, float& s32, int& K, int& d, double& a) {
  const double l2   = log10(2.0);
  const double l204 = log10(204.0);
  double step = (l204 - l2) / 127.0;
  double e = (i == 127) ? l204 : ((double)i * step + l2);
  double sv = pow(10.0, e);
  s32 = (float)sv;
  double sp = (double)s32;
  K = (int)ceil(sp * 16.0 + 1.0);
  d = (4094 - K) >> 1;
  a = sp * (16.0 / 4095.0);
}

// ---------------- build reflect-padded, interleaved signals ----------------
__global__ void k_build_xp(const float* __restrict__ x, float* __restrict__ xp4) {
  int idx = blockIdx.x * blockDim.x + threadIdx.x;   // 8192*128 threads
  int j    = idx & 3;
  int sig  = (idx >> 2) & 127;
  int mblk = idx >> 9;
  int p    = mblk * 4 + j;
  float val = 0.f;
  if (sig < 96 && p < C_TP) {
    int c = sig >> 5;
    int b = sig & 31;
    int t = p - 2047;
    if (t < 0) t = -t;                 // x[2047-p]
    else if (t > 4095) t = 8190 - t;   // x[10237-p]
    val = x[(b * 4096 + t) * 3 + c];
  }
  xp4[idx] = val;
}

// ---------------- zero OT (atomic accumulation target) ----------------
__global__ void k_zero(float* __restrict__ p, int n4) {
  int idx = blockIdx.x * blockDim.x + threadIdx.x;
  if (idx < n4) ((float4*)p)[idx] = make_float4(0.f, 0.f, 0.f, 0.f);
}

// ---------------- build composite kernels H ----------------
__global__ __launch_bounds__(256) void k_build_H(const float* __restrict__ int_psi,
                                                 float* __restrict__ Hbuf,
                                                 int* __restrict__ meta) {
  int i   = blockIdx.x;   // scale
  int cls = blockIdx.y;   // class

  float s32; int K, d; double a;
  scale_params(i, s32, K, d, a);

  int wr = (cls < 7) ? ((cls == 0) ? 7 : cls) : ((cls == 7) ? 0 : 223);
  double ks = 4096.0 / 224.0;
  double sf = ((double)wr + 0.5) * ks - 0.5;
  int t_lo = (int)floor(sf - ks) + 1;
  int t_hi = (int)ceil(sf + ks) - 1;
  if (t_lo < 0) t_lo = 0;
  if (t_hi > 4095) t_hi = 4095;
  int nt  = t_hi - t_lo + 1;   // <= 37
  int npv = nt + 1;            // conv-point weights

  __shared__ double Wt_sh[40];
  __shared__ double v_sh[64];
  __shared__ float  kern_sh[3352];

  // zero this block's full row
  float* rowFull = Hbuf + (long long)(i * C_NCLS + cls) * C_HSTRIDE;
  for (int q = threadIdx.x; q < (int)C_HSTRIDE; q += 256) rowFull[q] = 0.f;

  if (threadIdx.x == 0) {
    double Z = 0.0;
    for (int t = 0; t < nt; ++t) {
      double wv = 1.0 - fabs(sf - (double)(t + t_lo)) / ks;
      if (wv < 0.0) wv = 0.0;
      Wt_sh[t] = wv; Z += wv;
    }
    for (int t = 0; t < nt; ++t) Wt_sh[t] = Wt_sh[t] / Z;
    double sq = sqrt((double)s32);
    // v[p_lo + q] = -sqrt(s) * (Wt[q-1] - Wt[q])
    for (int q = 0; q <= nt; ++q) {
      double wm1 = (q >= 1)  ? Wt_sh[q - 1] : 0.0;
      double w0  = (q < nt)  ? Wt_sh[q]     : 0.0;
      v_sh[q] = -sq * (wm1 - w0);
    }
  }

  // flipped gathered wavelet: kernW[tau] = int_psi[clip(floor((K-1-tau)/a))]
  float* kernp = kern_sh + 40;
  int fillN = K + 80;
  for (int q = threadIdx.x; q < fillN; q += 256) {
    int tau = q - 40;
    float kv = 0.f;
    if (tau >= 0 && tau < K) {
      int u = K - 1 - tau;
      int jj = (int)floor((double)u / a);
      jj = jj < 0 ? 0 : (jj > 4095 ? 4095 : jj);
      kv = int_psi[jj];
    }
    kern_sh[q] = kv;
  }
  __syncthreads();

  int p_lo = t_lo + d;
  int Lh   = K + npv - 1;
  int kr   = (cls == 0) ? 1 : ((cls == 8) ? 31 : 0);
  int off0 = p_lo - 128 * kr;
  int shift = off0 & 3;
  int offA  = off0 - shift;
  int rowLen = (shift + Lh + 3) & ~3;

  float* row = Hbuf + (long long)(i * C_NCLS + cls) * C_HSTRIDE + C_HGUARD;
  for (int q = threadIdx.x; q < Lh; q += 256) {
    double acc = 0.0;
    for (int t = 0; t < npv; ++t) acc += v_sh[t] * (double)kernp[q - t];
    row[shift + q] = (float)acc;
  }
  if (threadIdx.x == 0) {
    meta[(i * C_NCLS + cls) * 2 + 0] = offA;
    meta[(i * C_NCLS + cls) * 2 + 1] = rowLen;
  }
}

// ---------------- main: OT[scale][w][sig] += sum_{m in piece} xp[m][sig]*H_w[m] ----------
// grid (piece, chunk, scale'), scale' reversed so heavy scales dispatch first.
__global__ __launch_bounds__(128, 8) void k_cwt_main(const float4* __restrict__ xp4,
                                                     const float* __restrict__ Hbuf,
                                                     const int* __restrict__ meta,
                                                     float* __restrict__ OT) {
  int piece = blockIdx.x;           // 0..3
  int chunk = blockIdx.y;           // 0..55
  int i     = 127 - blockIdx.z;     // heavy scales first
  int sig   = threadIdx.x;          // 0..127 (>=96 compute zeros)

  float acc[C_RW];
  const float* P[C_RW];
  int U0 = 0x7fffffff, U1 = 0;
#pragma unroll
  for (int j = 0; j < C_RW; ++j) {
    acc[j] = 0.f;
    int w = chunk * C_RW + j;
    int cls = (w == 0) ? 7 : ((w == 223) ? 8 : (w % 7));
    int k = w / 7;
    int base = i * C_NCLS + cls;
    int offA = meta[base * 2 + 0];
    int rl   = meta[base * 2 + 1];
    int start = offA + 128 * k;           // 4-aligned by construction
    if (start < U0) U0 = start;
    if (start + rl > U1) U1 = start + rl;
    P[j] = Hbuf + ((long long)base * C_HSTRIDE + C_HGUARD - start);
  }

  int m0 = U0 + piece * C_M;
  int m1 = m0 + C_M; if (m1 > U1) m1 = U1;
  if (m0 >= m1) return;

  // ---- software pipeline: x depth-2 (VGPR), H depth-1 (SGPR) ----
  // All overreads land in H zero-guards / within xp4 (max m index < 8192-24).
  const float4* xr = xp4 + ((long long)(m0 >> 2) * C_SIGP + sig);
  float4 xa0 = xr[0];
  float4 xb0 = xr[C_SIGP];
  float4 xa1 = xr[2 * C_SIGP];
  float4 xb1 = xr[3 * C_SIGP];
  xr += 4 * C_SIGP;

  float4 ha0[C_RW], hb0[C_RW];
#pragma unroll
  for (int j = 0; j < C_RW; ++j) {
    ha0[j] = *(const float4*)(P[j] + m0);      // uniform -> s_load_dwordx4
    hb0[j] = *(const float4*)(P[j] + m0 + 4);
  }

  for (int m = m0; m < m1; m += 8) {
    // issue loads for m+16 (x) and m+8 (H) before computing with current regs
    float4 xa2 = xr[0];
    float4 xb2 = xr[C_SIGP];
    xr += 2 * C_SIGP;
    float4 ha1[C_RW], hb1[C_RW];
#pragma unroll
    for (int j = 0; j < C_RW; ++j) {
      ha1[j] = *(const float4*)(P[j] + m + 8);
      hb1[j] = *(const float4*)(P[j] + m + 12);
    }
#pragma unroll
    for (int j = 0; j < C_RW; ++j) {
      acc[j] += xa0.x * ha0[j].x + xa0.y * ha0[j].y + xa0.z * ha0[j].z + xa0.w * ha0[j].w;
      acc[j] += xb0.x * hb0[j].x + xb0.y * hb0[j].y + xb0.z * hb0[j].z + xb0.w * hb0[j].w;
    }
    // rotate
    xa0 = xa1; xb0 = xb1; xa1 = xa2; xb1 = xb2;
#pragma unroll
    for (int j = 0; j < C_RW; ++j) { ha0[j] = ha1[j]; hb0[j] = hb1[j]; }
  }

#pragma unroll
  for (int j = 0; j < C_RW; ++j) {
    int w = chunk * C_RW + j;
    atomicAdd(&OT[((long long)i * C_NW + w) * C_SIGP + sig], acc[j]);
  }
}

// ---------------- final: scale-dim bilinear upsample 128->224 + layout ----------------
__global__ __launch_bounds__(256) void k_final(const float* __restrict__ OT,
                                               float* __restrict__ out) {
  int wt = blockIdx.x;    // 0..27
  int h  = blockIdx.y;    // 0..223

  float inv = 128.0f / 224.0f;               // f32 like jax
  float sg = ((float)h + 0.5f) * inv - 0.5f;
  float sgf = floorf(sg);
  int s0 = (int)sgf;
  float fr = sg - sgf;
  int r0, r1;
  if (s0 < 0)        { r0 = 0;   r1 = 0;   fr = 0.f; }
  else if (s0 >= 127){ r0 = 127; r1 = 127; fr = 0.f; }
  else               { r0 = s0;  r1 = s0 + 1; }

  __shared__ float sh0[8 * 132];
  __shared__ float sh1[8 * 132];
  for (int q = threadIdx.x; q < 1024; q += 256) {
    int wp  = q >> 7;
    int sg2 = q & 127;
    int wg  = wt * 8 + wp;
    sh0[wp * 132 + sg2] = OT[((long long)r0 * C_NW + wg) * C_SIGP + sg2];
    sh1[wp * 132 + sg2] = OT[((long long)r1 * C_NW + wg) * C_SIGP + sg2];
  }
  __syncthreads();

  int b  = threadIdx.x >> 3;    // 0..31
  int wp = threadIdx.x & 7;     // 0..7
  int obase = ((b * 224 + h) * 224 + wt * 8 + wp) * 3;
#pragma unroll
  for (int c = 0; c < 3; ++c) {
    int sidx = wp * 132 + c * 32 + b;
    float a0 = sh0[sidx];
    float a1 = sh1[sidx];
    out[obase + c] = (1.0f - fr) * a0 + fr * a1;
  }
}

// ---------------- launch ----------------
extern "C" void kernel_launch(void* const* d_in, const int* in_sizes, int n_in,
                              void* d_out, int out_size, void* d_ws, size_t ws_size,
                              hipStream_t stream) {
  const float* x       = (const float*)d_in[0];   // (32,4096,3) f32
  const float* int_psi = (const float*)d_in[1];   // (4096,) f32
  float* out = (float*)d_out;

  // workspace layout: xp4 (4 MB) | Hbuf (17.4 MB) | meta (9 KB) | OT (14.7 MB)
  float* xp4  = (float*)d_ws;                                   // 8192*128 floats
  float* Hbuf = xp4 + (long long)C_XROWS * C_SIGP;              // 1152*3776 floats
  int*   meta = (int*)(Hbuf + (long long)128 * C_NCLS * C_HSTRIDE); // 2304 ints
  float* OT   = (float*)(meta + 2304);                          // 128*224*128 floats

  int otN = 128 * C_NW * C_SIGP;
  k_zero<<<dim3(otN / 4 / 256), dim3(256), 0, stream>>>(OT, otN / 4);
  k_build_xp<<<dim3((C_XROWS * C_SIGP) / 256), dim3(256), 0, stream>>>(x, xp4);
  k_build_H<<<dim3(128, C_NCLS), dim3(256), 0, stream>>>(int_psi, Hbuf, meta);
  k_cwt_main<<<dim3(C_NP, C_NCH, 128), dim3(128), 0, stream>>>((const float4*)xp4, Hbuf, meta, OT);
  k_final<<<dim3(28, 224), dim3(256), 0, stream>>>(OT, out);
}